// Round 10
// baseline (186.598 us; speedup 1.0000x reference)
//
#include <hip/hip_runtime.h>
#include <hip/hip_bf16.h>

#define NB 64
#define S_ 1024
#define D_ 128

typedef __attribute__((ext_vector_type(8))) short bf16x8;
typedef __attribute__((ext_vector_type(4))) float f32x4;
typedef __attribute__((ext_vector_type(4))) unsigned int u32x4;

// Fragment-tiled layout: operands stored as 16-row x 32-k panels of 1KB,
// element (r,k) at short-offset (((k>>3)&3)*16 + (r&15))*8 + (k&7) ==
// lane*8 + j in MFMA A/B fragment order -> a wave fragment load/store is
// base + lane*16B: one coalesced 1KB transaction.

__device__ __forceinline__ unsigned short f2bf(float f) {
  __hip_bfloat16 h = __float2bfloat16(f);
  return __builtin_bit_cast(unsigned short, h);
}

__device__ __forceinline__ void async_copy16(const void* g, void* l) {
  __builtin_amdgcn_global_load_lds(
      (const __attribute__((address_space(1))) unsigned int*)g,
      (__attribute__((address_space(3))) unsigned int*)l, 16, 0, 0);
}

// Device-scope (MALL write-through) 16B store: publishes producer data so
// consumers on ANY XCD see it after the paired atomic flag — correctness does
// not depend on blockIdx->XCD mapping (Guideline 16). sc1 = device scope.
__device__ __forceinline__ void store16_dev(void* p, bf16x8 v) {
  u32x4 d = __builtin_bit_cast(u32x4, v);
  asm volatile("global_store_dwordx4 %0, %1, off sc1" ::"v"(p), "v"(d)
               : "memory");
}

// Bounded spins on MALL-coherent relaxed atomics (R5/R6-proven protocol;
// worst case ~tens of ms then loud failure, never a GPU hang).
__device__ __forceinline__ void spin_mask(unsigned* p, unsigned need) {
  if (threadIdx.x == 0) {
    int guard = 0;
    while ((__hip_atomic_load(p, __ATOMIC_RELAXED, __HIP_MEMORY_SCOPE_AGENT) &
            need) != need) {
      __builtin_amdgcn_s_sleep(1);
      if (++guard > 2000000) break;
    }
  }
  __syncthreads();
  asm volatile("" ::: "memory");
}

__device__ __forceinline__ void spin_cnt(unsigned* p, unsigned need) {
  if (threadIdx.x == 0) {
    int guard = 0;
    while (__hip_atomic_load(p, __ATOMIC_RELAXED, __HIP_MEMORY_SCOPE_AGENT) <
           need) {
      __builtin_amdgcn_s_sleep(1);
      if (++guard > 2000000) break;
    }
  }
  __syncthreads();
  asm volatile("" ::: "memory");
}

// Drain own stores to coherence point, then one flag-set per block.
__device__ __forceinline__ void publish_bit(unsigned* p, unsigned bit) {
  asm volatile("s_waitcnt vmcnt(0)" ::: "memory");
  __syncthreads();
  if (threadIdx.x == 0)
    __hip_atomic_fetch_or(p, bit, __ATOMIC_RELAXED, __HIP_MEMORY_SCOPE_AGENT);
}

// ------------- causal batched GEMM phase (N-split): LDS A, direct B ---------
// Block computes 64 t-rows (tile mt) x 64 d-cols (half nh); wave owns 64m x
// 16n (acc 8 VGPR). A staged in 16KB half-panels (4 chunks x 4 row-panels,
// thread t stages chunk hp*4+wave of row-panel jc, gated wave<rem), simple
// 2-phase barriers (R9: pipelining is neutral). B: direct global->VGPR, 1KB
// coalesced per fragment, depth-4 rolling prefetch. Dependency spins are done
// by the CALLER; this is pure compute.
template <bool HSWISH>
__device__ __forceinline__ void gemm_phase(
    unsigned short* ldsA, const int b, const int mt, const int nh,
    const unsigned short* __restrict__ Af, const unsigned short* __restrict__ Bf,
    unsigned short* __restrict__ Uf, const float* __restrict__ Xres,
    float* __restrict__ Out) {
  const int t = threadIdx.x;
  const int wave = t >> 6, lane = t & 63;
  const int quad = lane >> 4, l16 = lane & 15;

  const int cend = 2 * (mt + 1);       // active 32-k chunks (even, 2..32)
  const int nhp = (cend + 3) >> 2;     // 16KB half-panels

  const unsigned short* Ab = Af + (size_t)mt * 4 * 32 * 512;
  const unsigned short* Bb = Bf + (size_t)b * (D_ * S_);
  const int pcol = nh * 4 + wave;      // d-panel this wave consumes (0..7)

  f32x4 acc[4] = {};
  bf16x8 Bp[4];
#pragma unroll
  for (int g = 0; g < 4; ++g) {
    const int gg = (g < cend) ? g : 0;
    Bp[g] = *(const bf16x8*)(Bb + ((size_t)pcol * 32 + gg) * 512 + lane * 8);
  }

  for (int hp = 0; hp < nhp; ++hp) {
    __syncthreads();                   // prior-phase LDS readers done
    const int rem = cend - hp * 4;
    if (wave < rem) {                  // wave-uniform gate
#pragma unroll
      for (int jc = 0; jc < 4; ++jc)   // stage A[jc][hp*4+wave] lane-slice
        async_copy16(Ab + ((size_t)jc * 32 + hp * 4 + wave) * 512 + lane * 8,
                     ldsA + ((size_t)jc * 256 + t) * 8);
    }
    __syncthreads();                   // drains vmcnt; half-panel ready
#pragma unroll
    for (int c = 0; c < 4; ++c) {
      const int g = hp * 4 + c;
      if (g < cend) {
        bf16x8 af[4];
#pragma unroll
        for (int i = 0; i < 4; ++i)
          af[i] = *(const bf16x8*)(ldsA + i * 2048 + c * 512 + lane * 8);
        __builtin_amdgcn_s_setprio(1);
#pragma unroll
        for (int i = 0; i < 4; ++i)
          acc[i] = __builtin_amdgcn_mfma_f32_16x16x32_bf16(af[i], Bp[c],
                                                           acc[i], 0, 0, 0);
        __builtin_amdgcn_s_setprio(0);
      }
      const int gn = (g + 4 < cend) ? (g + 4) : 0;
      Bp[c] = *(const bf16x8*)(Bb + ((size_t)pcol * 32 + gn) * 512 + lane * 8);
    }
  }

  if (HSWISH) {
    __syncthreads();                   // done with staging; reuse LDS
    unsigned short* ldsT = ldsA;       // [d 64][t 64 + 4 pad]
#pragma unroll
    for (int i = 0; i < 4; ++i) {
      ushort4 pk;
      float v0 = acc[i][0], v1 = acc[i][1], v2 = acc[i][2], v3 = acc[i][3];
      pk.x = f2bf(v0 * fminf(fmaxf(v0 + 3.f, 0.f), 6.f) * (1.f / 6.f));
      pk.y = f2bf(v1 * fminf(fmaxf(v1 + 3.f, 0.f), 6.f) * (1.f / 6.f));
      pk.z = f2bf(v2 * fminf(fmaxf(v2 + 3.f, 0.f), 6.f) * (1.f / 6.f));
      pk.w = f2bf(v3 * fminf(fmaxf(v3 + 3.f, 0.f), 6.f) * (1.f / 6.f));
      const int n = wave * 16 + l16;   // d within 64-col block
      const int m0 = i * 16 + quad * 4;
      *(ushort4*)(ldsT + n * 68 + m0) = pk;
    }
    __syncthreads();
    unsigned short* gU = Uf + (size_t)b * (D_ * S_);
#pragma unroll
    for (int ff = 0; ff < 2; ++ff) {   // 8 fragments over 4 waves
      const int cl = ff;
      const int d = wave * 16 + l16;
      const int tb = cl * 32 + quad * 8;
      bf16x8 v = *(const bf16x8*)(ldsT + d * 68 + tb);
      store16_dev(gU + ((size_t)(nh * 4 + wave) * 32 + mt * 2 + cl) * 512 +
                      lane * 8,
                  v);
    }
  } else {
    float* gO = Out + (size_t)b * S_ * D_;
    const float* gX = Xres + (size_t)b * S_ * D_;
    const int col = nh * 64 + wave * 16 + l16;
#pragma unroll
    for (int i = 0; i < 4; ++i) {
      const int mrow0 = mt * 64 + i * 16 + quad * 4;
#pragma unroll
      for (int r = 0; r < 4; ++r) {
        const int addr = (mrow0 + r) * D_ + col;
        gO[addr] = gX[addr] + acc[i][r];
      }
    }
  }
}

// ---- mega (grid 2048 = 8 blocks/CU, 32 waves/CU): ---------------------------
// nh=0 blocks: stats -> norm -> hTf publish (exact R6 code). nh=1 blocks:
// W-pack (4096 waves = 4096 fragment-chunks) on otherwise-idle slots,
// publish via global wcnt. Then ALL blocks: gemm1 (tile mt, cols 64nh..)
// after wcnt+h-bit spins, publish u-bit in per-nh mask; gemm2 after both
// u-masks. All sync via MALL-coherent atomics + sc1 data stores; DAG acyclic;
// all 2048 blocks resident (17KB LDS, VGPR<=64 via launch_bounds(256,8)).
// Per-CU balance: each CU hosts j in {c,c+4,c+8,c+12} x both halves ->
// sum(cend)=68 per half-set per gemm, both gemms.
__global__ __launch_bounds__(256, 8) void mega_kernel(
    const float* __restrict__ x, const float* __restrict__ ln_w,
    const float* __restrict__ ln_b, const float* __restrict__ W1,
    const float* __restrict__ W2, float* __restrict__ stats,
    unsigned short* __restrict__ W1f, unsigned short* __restrict__ W2f,
    unsigned short* __restrict__ hTf, unsigned short* __restrict__ uTf,
    float* __restrict__ out) {
  __shared__ __align__(16) unsigned short smem[8480];   // 16.96 KB

  const int bi = blockIdx.x;           // 0..2047
  const int xcd = bi & 7;              // perf heuristic only (L2 locality)
  const int slot = bi >> 3;            // 0..255
  const int b = xcd * 8 + (slot & 7);  // batch stays on one XCD
  const int r = slot >> 3;             // 0..31
  const int j = r & 15;
  const int mt = (j < 8) ? j : (j ^ 3);
  const int nh = r >> 4;               // 0..1 (d-column half)

  const int t = threadIdx.x;
  const int wave = t >> 6, lane = t & 63;
  const int quad = lane >> 4, l16 = lane & 15;

  float* sb = stats + (size_t)b * 32;  // 128B/batch slot
  unsigned* cntp = (unsigned*)sb + 2;
  unsigned* hmp = (unsigned*)sb + 4;
  unsigned* ump0 = (unsigned*)sb + 6;
  unsigned* ump1 = (unsigned*)sb + 8;
  unsigned* wcnt = (unsigned*)stats + 16;  // global W-pack counter (slot b=0)

  if (nh == 0) {
    // ---------- stats (own s-tile = rows 64mt..64mt+63) ---------------------
    float2* w4 = (float2*)(smem + 8448);
    float* mr = (float*)(smem + 8464);
    const float4* xb = (const float4*)(x + ((size_t)b * S_ + mt * 64) * D_);
    {
      float s = 0.f, q = 0.f;
#pragma unroll
      for (int i = 0; i < 8; ++i) {
        float4 v = xb[i * 256 + t];
        s += v.x + v.y + v.z + v.w;
        q += v.x * v.x + v.y * v.y + v.z * v.z + v.w * v.w;
      }
#pragma unroll
      for (int o = 32; o > 0; o >>= 1) {
        s += __shfl_down(s, o, 64);
        q += __shfl_down(q, o, 64);
      }
      if (lane == 0) w4[wave] = make_float2(s, q);
    }
    __syncthreads();
    if (t == 0) {
      float ss = 0.f, qq = 0.f;
#pragma unroll
      for (int i = 0; i < 4; ++i) { ss += w4[i].x; qq += w4[i].y; }
      float o1 = __hip_atomic_fetch_add(sb + 0, ss, __ATOMIC_RELAXED,
                                        __HIP_MEMORY_SCOPE_AGENT);
      float o2 = __hip_atomic_fetch_add(sb + 1, qq, __ATOMIC_RELAXED,
                                        __HIP_MEMORY_SCOPE_AGENT);
      asm volatile("" ::"v"(o1), "v"(o2));  // adds complete before cnt bump
      __hip_atomic_fetch_add(cntp, 1u, __ATOMIC_RELAXED,
                             __HIP_MEMORY_SCOPE_AGENT);
      int guard = 0;
      while (__hip_atomic_load(cntp, __ATOMIC_RELAXED,
                               __HIP_MEMORY_SCOPE_AGENT) < 16u) {
        __builtin_amdgcn_s_sleep(1);
        if (++guard > 2000000) break;
      }
      float s1 = __hip_atomic_load(sb + 0, __ATOMIC_RELAXED,
                                   __HIP_MEMORY_SCOPE_AGENT);
      float s2 = __hip_atomic_load(sb + 1, __ATOMIC_RELAXED,
                                   __HIP_MEMORY_SCOPE_AGENT);
      const float inv = 1.0f / (S_ * D_);
      const float mu = s1 * inv;
      mr[0] = mu;
      mr[1] = rsqrtf(s2 * inv - mu * mu + 1e-5f);
    }
    __syncthreads();
    const float mu = mr[0];
    const float rs = mr[1];

    // ---------- normalize (x L1/L2-hot) + LDS [s][d+4pad] transpose ---------
    {
      unsigned short* lds = smem;
      const float4* wb = (const float4*)(ln_w + (size_t)(mt * 64) * D_);
      const float4* bv4 = (const float4*)(ln_b + (size_t)(mt * 64) * D_);
#pragma unroll
      for (int rr = 0; rr < 8; ++rr) {
        const int f = rr * 256 + t;
        const int srow = f >> 5;
        const int c4 = f & 31;
        float4 xv = xb[f];
        float4 wv = wb[f];
        float4 bvv = bv4[f];
        ushort4 o;
        o.x = f2bf((xv.x - mu) * rs * wv.x + bvv.x);
        o.y = f2bf((xv.y - mu) * rs * wv.y + bvv.y);
        o.z = f2bf((xv.z - mu) * rs * wv.z + bvv.z);
        o.w = f2bf((xv.w - mu) * rs * wv.w + bvv.w);
        *(ushort4*)(lds + srow * 132 + c4 * 4) = o;
      }
      __syncthreads();
      unsigned short* outp = hTf + (size_t)b * (D_ * S_);
      const int cg0 = mt * 2;
#pragma unroll
      for (int ff = 0; ff < 4; ++ff) {
        const int f = wave * 4 + ff;   // 16 fragments per block
        const int p = f >> 1, cl = f & 1;
        const int d = p * 16 + l16;
        const int sbase = cl * 32 + quad * 8;
        bf16x8 v;
#pragma unroll
        for (int jj = 0; jj < 8; ++jj)
          v[jj] = (short)lds[(sbase + jj) * 132 + d];
        store16_dev(outp + ((size_t)p * 32 + cg0 + cl) * 512 + lane * 8, v);
      }
    }
    publish_bit(hmp, 1u << mt);
  } else {
    // ---------- W-pack on otherwise-idle nh=1 blocks ------------------------
    // Dense idx 0..1023 -> wave u = idx*4+wave covers all 4096 chunks.
    const int idx = xcd * 128 + (slot & 7) * 16 + (r - 16);
    const int u = idx * 4 + wave;
    const int f = u & 2047;
    const int p = f >> 5, c = f & 31;
    const int rr = p * 16 + l16;
    const int k0 = c * 32 + quad * 8;
    const float* wsrc = ((u >> 11) ? W2 : W1) + (size_t)rr * 1024 + k0;
    float4 a0 = ((const float4*)wsrc)[0];
    float4 a1 = ((const float4*)wsrc)[1];
    float av[8] = {a0.x, a0.y, a0.z, a0.w, a1.x, a1.y, a1.z, a1.w};
    bf16x8 o;
#pragma unroll
    for (int jj = 0; jj < 8; ++jj)
      o[jj] = (short)f2bf((k0 + jj <= rr) ? av[jj] : 0.f);
    unsigned short* dstp = ((u >> 11) ? W2f : W1f) +
                           ((size_t)p * 32 + c) * 512 + lane * 8;
    store16_dev(dstp, o);              // consumed cross-XCD -> device scope
    asm volatile("s_waitcnt vmcnt(0)" ::: "memory");
    __syncthreads();
    if (t == 0)
      __hip_atomic_fetch_add(wcnt, 1u, __ATOMIC_RELAXED,
                             __HIP_MEMORY_SCOPE_AGENT);
  }

  // ---------- gemm1: u = hardswish(W1c @ h), tile (mt, nh) ------------------
  spin_cnt(wcnt, 1024);                // W1f/W2f fully packed
  spin_mask(hmp, (2u << mt) - 1);      // h chunks 0..cend-1 published
  gemm_phase<true>(smem, b, mt, nh, W1f, hTf, uTf, nullptr, nullptr);
  publish_bit(nh ? ump1 : ump0, 1u << mt);

  // ---------- gemm2: out = x + W2c @ u, tile (mt, nh) -----------------------
  spin_mask(ump0, (2u << mt) - 1);     // u chunks complete needs BOTH halves
  spin_mask(ump1, (2u << mt) - 1);
  gemm_phase<false>(smem, b, mt, nh, W2f, uTf, nullptr, x, out);
}

extern "C" void kernel_launch(void* const* d_in, const int* in_sizes, int n_in,
                              void* d_out, int out_size, void* d_ws, size_t ws_size,
                              hipStream_t stream) {
  const float* x = (const float*)d_in[0];
  const float* ln_w = (const float*)d_in[1];
  const float* ln_b = (const float*)d_in[2];
  const float* W1 = (const float*)d_in[3];
  const float* W2 = (const float*)d_in[4];
  float* out = (float*)d_out;

  char* ws = (char*)d_ws;
  float* stats = (float*)ws;                                 // 8 KiB (64x128B)
  unsigned short* W1f = (unsigned short*)(ws + 16384);       // 2 MiB
  unsigned short* W2f = W1f + (size_t)S_ * S_;               // 2 MiB
  unsigned short* hTf = W2f + (size_t)S_ * S_;               // 16 MiB
  unsigned short* uTf = hTf + (size_t)NB * D_ * S_;          // 16 MiB

  hipMemsetAsync(stats, 0, 8192, stream);   // zero stats/flag slots (capture-safe)
  mega_kernel<<<2048, 256, 0, stream>>>(x, ln_w, ln_b, W1, W2, stats,
                                        W1f, W2f, hTf, uTf, out);
}